// Round 7
// baseline (326.176 us; speedup 1.0000x reference)
//
#include <hip/hip_runtime.h>
#include <stdint.h>

// ---------------------------------------------------------------------------
// DS_MultiHeadLatentAttention, round 7.
// Change vs round 6 (isolated): GEMM K-loop restructured to a register-
// prefetch pipeline -- global loads for iter k+1 issue before iter k's MFMA
// section, so the HBM/L2 latency that round 6 exposed at the vmcnt(0) barrier
// drain (2 blocks/CU -> no co-resident overlap) is hidden behind compute.
// LDS writes reuse the exact contiguous lane*16B layout gl16 produced.
// attn6 / prep unchanged.
// Dispatches: prep, gemmQLat(640), gemmKV(1024), attn(512), gemmO(512).
// Workspace (34 MB, time-phased):
//   [0,8M)   Qp      [8,16M)  Kb -> Kp      [16,24M) Qb -> VpT
//   [24,32M) WqT(2M)|Lat(2M)|WdT(.5M)|WkvT(1M) -> Attn
//   [32,34M) WoT
// ---------------------------------------------------------------------------

#define DM 1024
#define NH 16
#define DK 64
#define LL 2048

typedef float  f32x4  __attribute__((ext_vector_type(4)));
typedef __bf16 bf16x8 __attribute__((ext_vector_type(8)));
typedef short  s16x8  __attribute__((ext_vector_type(8)));

__device__ __forceinline__ unsigned short f2bf(float f) {
    union { float f; unsigned int u; } v; v.f = f;
    return (unsigned short)((v.u + 0x7fffu + ((v.u >> 16) & 1u)) >> 16);
}
__device__ __forceinline__ unsigned int pack2(float a, float b) {
    return (unsigned int)f2bf(a) | ((unsigned int)f2bf(b) << 16);
}
__device__ __forceinline__ bf16x8 ld8(const unsigned short* p) {
    s16x8 s = *(const s16x8*)p;
    return __builtin_bit_cast(bf16x8, s);
}
__device__ __forceinline__ void gl16(const void* g, void* l) {
    __builtin_amdgcn_global_load_lds((__attribute__((address_space(1))) void*)(g),
                                     (__attribute__((address_space(3))) void*)(l),
                                     16, 0, 0);
}

// ---------------------------------------------------------------------------
// prep: 5 weight transposes (fp32 [K][N] -> bf16 [N][K]) + queries/keys
// fp32 -> bf16. Grid = 4864.
// ---------------------------------------------------------------------------
__global__ __launch_bounds__(256)
void prep_k(const float* __restrict__ Wq, const float* __restrict__ Wd,
            const float* __restrict__ Wk, const float* __restrict__ Wv,
            const float* __restrict__ Wo, const float* __restrict__ queries,
            const float* __restrict__ keys,
            unsigned short* __restrict__ WqT, unsigned short* __restrict__ WdT,
            unsigned short* __restrict__ WkvT, unsigned short* __restrict__ WoT,
            unsigned short* __restrict__ Qb, unsigned short* __restrict__ Kb) {
    int bid = blockIdx.x;
    const int t = threadIdx.x;

    const float* W; unsigned short* WT; int TK, TN;
    if (bid < 1024)      { W = Wq; WT = WqT;  TK = 1024; TN = 1024; }
    else if (bid < 1280) { bid -= 1024; W = Wd; WT = WdT; TK = 1024; TN = 256; }
    else if (bid < 1536) { bid -= 1280; W = Wk; WT = WkvT; TK = 256; TN = 1024; }
    else if (bid < 1792) { bid -= 1536; W = Wv; WT = WkvT + (size_t)1024 * 256; TK = 256; TN = 1024; }
    else if (bid < 2816) { bid -= 1792; W = Wo; WT = WoT;  TK = 1024; TN = 1024; }
    else {
        bid -= 2816;
        const float* src; unsigned short* dst;
        if (bid < 1024) { src = queries; dst = Qb; }
        else            { bid -= 1024; src = keys; dst = Kb; }
        const size_t base = (size_t)bid * 4096;
#pragma unroll
        for (int i = 0; i < 4; ++i) {
            float4 f = *(const float4*)(src + base + (size_t)(i * 256 + t) * 4);
            uint2 u = { pack2(f.x, f.y), pack2(f.z, f.w) };
            *(uint2*)(dst + base + (size_t)(i * 256 + t) * 4) = u;
        }
        return;
    }
    __shared__ float tile[32][33];
    const int tx = t & 31, ty = t >> 5;
    const int bx = bid % (TK / 32), by = bid / (TK / 32);
    const int k0 = bx * 32, n0 = by * 32;
#pragma unroll
    for (int i = 0; i < 4; ++i)
        tile[ty + 8 * i][tx] = W[(size_t)(k0 + ty + 8 * i) * TN + n0 + tx];
    __syncthreads();
#pragma unroll
    for (int i = 0; i < 4; ++i)
        WT[(size_t)(n0 + ty + 8 * i) * TK + k0 + tx] = f2bf(tile[tx][ty + 8 * i]);
}

// ---------------------------------------------------------------------------
// GEMM 128(M) x 64(N) tile, BK=64, 4 waves 2x2 (wave = 64m x 32n, 4x2 accs).
// Register-prefetch pipeline: iter k+1's global loads issue before iter k's
// MFMAs; vmcnt wait lands at the next iteration's ds_write.
// XCD-clustered: xcd = bid&7 sweeps all n over a small m-window.
// MODE 0: fused Q+Lat (K=1024). bid<512: Qb@WqT+bq -> Qp bf16 [row*1024].
//         bid>=512 (128 blocks): Kb@WdT+bd -> Lat bf16 [row*256].
// MODE 1: Attn@WoT+bo -> f32 [row*1024]. grid 512, K=1024.
// MODE 2: fused K|V (K=256, N=2048): col<1024 -> Kp bf16 [row*1024];
//         col>=1024 -> VpT [b][col-1024][l] via LDS-transposed epilogue.
// ---------------------------------------------------------------------------
template<int MODE>
__global__ __launch_bounds__(256)
void gemm_k(const unsigned short* __restrict__ Ap, const unsigned short* __restrict__ Bt,
            const float* __restrict__ bias, void* __restrict__ Cp,
            const unsigned short* __restrict__ Ap2, const unsigned short* __restrict__ Bt2,
            const float* __restrict__ bias2, void* __restrict__ Cp2,
            int K) {
    __shared__ unsigned short Sh[12288];      // As 128x64 (16KB) + Bs 64x64 (8KB)
    unsigned short* As = Sh;
    unsigned short* Bs = Sh + 8192;

    int bid = blockIdx.x;
    const unsigned short* A;
    const unsigned short* B;
    const float* bs;
    bool second = false;
    int m0, n0;
    if (MODE == 0 && bid >= 512) {            // Lat part: 128 blocks, N=256
        bid -= 512; A = Ap2; B = Bt2; bs = bias2; second = true;
        const int xcd = bid & 7, s = bid >> 3;            // s in [0,16)
        n0 = (s & 3) * 64; m0 = (xcd * 4 + (s >> 2)) * 128;
    } else {
        A = Ap; B = Bt; bs = bias;
        const int xcd = bid & 7, s = bid >> 3;
        if (MODE == 2) { n0 = (s & 31) * 64; m0 = (xcd * 4 + (s >> 5)) * 128; }
        else           { n0 = (s & 15) * 64; m0 = (xcd * 4 + (s >> 4)) * 128; }
    }

    const int t = threadIdx.x, lane = t & 63, wv = t >> 6;
    const int quad = lane >> 4, l15 = lane & 15;

    const int lr8 = lane >> 3;                 // 0..7
    const int g8 = (lane & 7) ^ (lr8 & 7);     // swizzled k-chunk
    const unsigned short* gA = A + (size_t)(m0 + wv * 32 + lr8) * K + g8 * 8;
    const unsigned short* gB = B + (size_t)(n0 + wv * 16 + lr8) * K + g8 * 8;
    unsigned short* lA = As + wv * 2048;       // 32 rows/wave
    unsigned short* lB = Bs + wv * 1024;       // 16 rows/wave

    int aoff[4][2], boff[2][2];
#pragma unroll
    for (int i = 0; i < 4; ++i) {
        const int ra = (wv >> 1) * 64 + i * 16 + l15;
#pragma unroll
        for (int ks = 0; ks < 2; ++ks)
            aoff[i][ks] = ra * 64 + (((ks * 4 + quad) ^ (ra & 7)) << 3);
    }
#pragma unroll
    for (int j = 0; j < 2; ++j) {
        const int rb = (wv & 1) * 32 + j * 16 + l15;
#pragma unroll
        for (int ks = 0; ks < 2; ++ks)
            boff[j][ks] = rb * 64 + (((ks * 4 + quad) ^ (rb & 7)) << 3);
    }

    // ---- register-prefetch pipeline ----
    uint4 rA[4], rB[2];
#pragma unroll
    for (int s = 0; s < 4; ++s) rA[s] = *(const uint4*)(gA + (size_t)s * 8 * K);
#pragma unroll
    for (int s = 0; s < 2; ++s) rB[s] = *(const uint4*)(gB + (size_t)s * 8 * K);

    f32x4 acc[4][2] = {};
    for (int kk = 0; kk < K; kk += 64) {
        __syncthreads();                       // previous iter's frag reads done
#pragma unroll
        for (int s = 0; s < 4; ++s)            // vmcnt wait lands here
            *(uint4*)(lA + s * 512 + lane * 8) = rA[s];
#pragma unroll
        for (int s = 0; s < 2; ++s)
            *(uint4*)(lB + s * 512 + lane * 8) = rB[s];
        __syncthreads();
        if (kk + 64 < K) {                     // prefetch next iter (in flight
#pragma unroll                                 //  during the MFMA section)
            for (int s = 0; s < 4; ++s)
                rA[s] = *(const uint4*)(gA + kk + 64 + (size_t)s * 8 * K);
#pragma unroll
            for (int s = 0; s < 2; ++s)
                rB[s] = *(const uint4*)(gB + kk + 64 + (size_t)s * 8 * K);
        }
#pragma unroll
        for (int ks = 0; ks < 2; ++ks) {
            bf16x8 a[4], b[2];
#pragma unroll
            for (int i = 0; i < 4; ++i) a[i] = ld8(As + aoff[i][ks]);
#pragma unroll
            for (int j = 0; j < 2; ++j) b[j] = ld8(Bs + boff[j][ks]);
#pragma unroll
            for (int i = 0; i < 4; ++i)
#pragma unroll
                for (int j = 0; j < 2; ++j)
                    acc[i][j] = __builtin_amdgcn_mfma_f32_16x16x32_bf16(a[i], b[j], acc[i][j], 0, 0, 0);
        }
    }

    const bool isV = (MODE == 2) && (n0 >= 1024);
    if (!isV) {
#pragma unroll
        for (int j = 0; j < 2; ++j) {
            const int col = n0 + (wv & 1) * 32 + j * 16 + l15;
            const float bvv = bs[col];
#pragma unroll
            for (int i = 0; i < 4; ++i) {
                const int rowb = m0 + (wv >> 1) * 64 + i * 16 + quad * 4;
#pragma unroll
                for (int r = 0; r < 4; ++r) {
                    const float v = acc[i][j][r] + bvv;
                    const int row = rowb + r;
                    if (MODE == 1)
                        ((float*)Cp)[(size_t)row * 1024 + col] = v;
                    else if (second)
                        ((unsigned short*)Cp2)[(size_t)row * 256 + col] = f2bf(v);
                    else
                        ((unsigned short*)Cp)[(size_t)row * 1024 + col] = f2bf(v);
                }
            }
        }
    } else {
        // V part: transpose 128tok x 64d tile through LDS, store coalesced
        // to VpT[(b*1024 + d)*2048 + l].  Ld layout: [d][tok], stride 136.
        __syncthreads();                        // all frag reads done; reuse Sh
        unsigned short* Ld = Sh;                // 64*136 shorts = 17408 B
#pragma unroll
        for (int j = 0; j < 2; ++j) {
            const int dloc = (wv & 1) * 32 + j * 16 + l15;
            const float bvv = bias2[(n0 - 1024) + dloc];
#pragma unroll
            for (int i = 0; i < 4; ++i) {
                const int tokb = (wv >> 1) * 64 + i * 16 + quad * 4;
#pragma unroll
                for (int r = 0; r < 4; ++r)
                    Ld[dloc * 136 + tokb + r] = f2bf(acc[i][j][r] + bvv);
            }
        }
        __syncthreads();
        const int dloc = t >> 2;                // 0..63
        const int tk0 = (t & 3) * 32;           // 0,32,64,96
        const int bb = m0 >> 11;
        unsigned short* dst = (unsigned short*)Cp2 +
            ((size_t)bb * 1024 + (n0 - 1024) + dloc) * LL + (m0 & (LL - 1)) + tk0;
        const unsigned short* srcp = Ld + dloc * 136 + tk0;
#pragma unroll
        for (int c = 0; c < 4; ++c)
            *(uint4*)(dst + c * 8) = *(const uint4*)(srcp + c * 8);
    }
}

// ---------------------------------------------------------------------------
// Causal attention: 512 thr (2 groups of 4 waves), paired q-tiles (j, 31-j),
// even/odd 64-key chunk split, fixed-shift softmax, diag-hoisted masking.
// Grid 512, XCD-clustered (each XCD owns 4 (h,b) combos).
// ---------------------------------------------------------------------------
__global__ __launch_bounds__(512)
void attn6_k(const unsigned short* __restrict__ Qp,
             const unsigned short* __restrict__ Kp,
             const unsigned short* __restrict__ VpT,
             unsigned short* __restrict__ Op) {
    __shared__ unsigned short Ks[2][4096];
    __shared__ unsigned short Vs[2][4096];
    __shared__ unsigned short Ps[8][16][72];

    const int t = threadIdx.x, lane = t & 63, wv = t >> 6;
    const int grp = wv >> 2, w4 = wv & 3;
    const int quad = lane >> 4, l15 = lane & 15;

    const int bid = blockIdx.x;
    const int xcd = bid & 7, s = bid >> 3;
    const int pair = s & 15;
    const int combo = xcd * 4 + (s >> 4);
    const int h = combo & 15, b = combo >> 4;

    const int srow = w4 * 16 + (lane >> 3);
    const int g8 = (lane & 7) ^ ((lane >> 3) & 7);
    unsigned short* lK = &Ks[grp][w4 * 1024];
    unsigned short* lV = &Vs[grp][w4 * 1024];
    const int sw = l15 & 7;
    float* cb = (float*)&Ks[0][0];

    for (int tsel = 0; tsel < 2; ++tsel) {
        const int tile = tsel ? (31 - pair) : pair;
        const int q0 = tile * 64;

        const unsigned short* qp = Qp + (size_t)(b * LL + q0 + w4 * 16 + l15) * DM + h * DK;
        const bf16x8 aq0 = ld8(qp + quad * 8);
        const bf16x8 aq1 = ld8(qp + 32 + quad * 8);

        f32x4 acc[4] = {};
        float lrow[4] = {0.f, 0.f, 0.f, 0.f};
        const int rowq = q0 + w4 * 16 + quad * 4;

        const int nit = tile / 2 + 1;
        for (int it = 0; it < nit; ++it) {
            const int c = 2 * it + grp;
            const bool active = (c <= tile);
            const int kt = c * 64;
            __syncthreads();
            if (active) {
                const unsigned short* kg = Kp + (size_t)(b * LL + kt + srow) * DM + h * DK + g8 * 8;
                const unsigned short* vg = VpT + ((size_t)(b * NH + h) * DK + srow) * LL + kt + g8 * 8;
                gl16(kg, lK);             gl16(kg + (size_t)8 * DM, lK + 512);
                gl16(vg, lV);             gl16(vg + (size_t)8 * LL, lV + 512);
            }
            __syncthreads();
            if (!active) continue;

            f32x4 s4[4];
#pragma unroll
            for (int sub = 0; sub < 4; ++sub) {
                const int base = (sub * 16 + l15) * 64;
                f32x4 ss = {};
                bf16x8 b0 = ld8(&Ks[grp][base + ((quad ^ sw) << 3)]);
                ss = __builtin_amdgcn_mfma_f32_16x16x32_bf16(aq0, b0, ss, 0, 0, 0);
                bf16x8 b1 = ld8(&Ks[grp][base + (((4 + quad) ^ sw) << 3)]);
                ss = __builtin_amdgcn_mfma_f32_16x16x32_bf16(aq1, b1, ss, 0, 0, 0);
                s4[sub] = ss;
            }

            if (c == tile) {                   // diagonal chunk: mask
#pragma unroll
                for (int sub = 0; sub < 4; ++sub) {
                    const int col = kt + sub * 16 + l15;
#pragma unroll
                    for (int r = 0; r < 4; ++r) {
                        float e = exp2f(fmaf(s4[sub][r], 0.18033688011112042f, -16.0f));
                        if (col > rowq + r) e = 0.f;
                        lrow[r] += e;
                        Ps[wv][quad * 4 + r][sub * 16 + l15] =
                            (unsigned short)(__builtin_bit_cast(unsigned int, e) >> 16);
                    }
                }
            } else {                           // interior: no mask
#pragma unroll
                for (int sub = 0; sub < 4; ++sub) {
#pragma unroll
                    for (int r = 0; r < 4; ++r) {
                        float e = exp2f(fmaf(s4[sub][r], 0.18033688011112042f, -16.0f));
                        lrow[r] += e;
                        Ps[wv][quad * 4 + r][sub * 16 + l15] =
                            (unsigned short)(__builtin_bit_cast(unsigned int, e) >> 16);
                    }
                }
            }

#pragma unroll
            for (int ks = 0; ks < 2; ++ks) {
                bf16x8 ap = ld8(&Ps[wv][l15][ks * 32 + quad * 8]);
#pragma unroll
                for (int sub = 0; sub < 4; ++sub) {
                    bf16x8 bv = ld8(&Vs[grp][(sub * 16 + l15) * 64 + (((ks * 4 + quad) ^ sw) << 3)]);
                    acc[sub] = __builtin_amdgcn_mfma_f32_16x16x32_bf16(ap, bv, acc[sub], 0, 0, 0);
                }
            }
        }

        __syncthreads();
        const int base = (w4 * 64 + lane) * 20;
        if (grp == 1) {
#pragma unroll
            for (int sub = 0; sub < 4; ++sub)
#pragma unroll
                for (int r = 0; r < 4; ++r) cb[base + sub * 4 + r] = acc[sub][r];
#pragma unroll
            for (int r = 0; r < 4; ++r) cb[base + 16 + r] = lrow[r];
        }
        __syncthreads();
        if (grp == 0) {
#pragma unroll
            for (int sub = 0; sub < 4; ++sub)
#pragma unroll
                for (int r = 0; r < 4; ++r) acc[sub][r] += cb[base + sub * 4 + r];
#pragma unroll
            for (int r = 0; r < 4; ++r) {
                lrow[r] += cb[base + 16 + r];
#pragma unroll
                for (int off = 1; off < 16; off <<= 1)
                    lrow[r] += __shfl_xor(lrow[r], off, 64);
                lrow[r] = __builtin_amdgcn_rcpf(lrow[r]);
            }
#pragma unroll
            for (int sub = 0; sub < 4; ++sub)
#pragma unroll
                for (int r = 0; r < 4; ++r)
                    Op[(size_t)(b * LL + rowq + r) * DM + h * DK + sub * 16 + l15] =
                        f2bf(acc[sub][r] * lrow[r]);
        }
    }
}

// ---------------------------------------------------------------------------
extern "C" void kernel_launch(void* const* d_in, const int* in_sizes, int n_in,
                              void* d_out, int out_size, void* d_ws, size_t ws_size,
                              hipStream_t stream) {
    const float* queries = (const float*)d_in[0];
    const float* keys    = (const float*)d_in[1];
    const float* Wq = (const float*)d_in[3];  const float* bq = (const float*)d_in[4];
    const float* Wd = (const float*)d_in[5];  const float* bd = (const float*)d_in[6];
    const float* Wk = (const float*)d_in[7];  const float* bk = (const float*)d_in[8];
    const float* Wv = (const float*)d_in[9];  const float* bv = (const float*)d_in[10];
    const float* Wo = (const float*)d_in[11]; const float* bo = (const float*)d_in[12];

    char* ws = (char*)d_ws;
    const size_t MB = 1048576;
    unsigned short* Qp   = (unsigned short*)(ws);
    unsigned short* Kb   = (unsigned short*)(ws + 8 * MB);
    unsigned short* Kp   = (unsigned short*)(ws + 8 * MB);
    unsigned short* Qb   = (unsigned short*)(ws + 16 * MB);
    unsigned short* VpT  = (unsigned short*)(ws + 16 * MB);
    unsigned short* WqT  = (unsigned short*)(ws + 24 * MB);
    unsigned short* Lat  = (unsigned short*)(ws + 26 * MB);
    unsigned short* WdT  = (unsigned short*)(ws + 28 * MB);
    unsigned short* WkvT = (unsigned short*)(ws + 28 * MB + 524288);
    unsigned short* Attn = (unsigned short*)(ws + 24 * MB);
    unsigned short* WoT  = (unsigned short*)(ws + 32 * MB);

    prep_k<<<4864, 256, 0, stream>>>(Wq, Wd, Wk, Wv, Wo, queries, keys,
                                     WqT, WdT, WkvT, WoT, Qb, Kb);
    gemm_k<0><<<640, 256, 0, stream>>>(Qb, WqT, bq, Qp, Kb, WdT, bd, Lat, 1024);
    gemm_k<2><<<1024, 256, 0, stream>>>(Lat, WkvT, bk, Kp, nullptr, nullptr, bv, VpT, 256);
    attn6_k<<<512, 512, 0, stream>>>(Qp, Kp, VpT, Attn);
    gemm_k<1><<<512, 256, 0, stream>>>(Attn, WoT, bo, d_out, nullptr, nullptr, nullptr, nullptr, 1024);
}

// Round 8
// 198.792 us; speedup vs baseline: 1.6408x; 1.6408x over previous
//
#include <hip/hip_runtime.h>
#include <stdint.h>

// ---------------------------------------------------------------------------
// DS_MultiHeadLatentAttention, round 8.
// Round 7's register-prefetch spilled to scratch (WRITE_SIZE 133 MB, 1.8 TB/s
// scratch stream) -- reverted. This round: LDS double-buffer with gl16 and
// compile-time buffer selection (two distinct __shared__ arrays, K-loop
// unrolled by 2) so ds_reads of the compute buffer don't wait on the
// in-flight gl16s of the prefetch buffer. One barrier per K-iter; the
// vmcnt(0) drain at the barrier lands after the MFMA section has already
// covered most of the load latency. attn6 / prep unchanged from round 6.
// Dispatches: prep, gemmQLat(640), gemmKV(1024), attn(512), gemmO(512).
// Workspace (34 MB, time-phased):
//   [0,8M)   Qp      [8,16M)  Kb -> Kp      [16,24M) Qb -> VpT
//   [24,32M) WqT(2M)|Lat(2M)|WdT(.5M)|WkvT(1M) -> Attn
//   [32,34M) WoT
// ---------------------------------------------------------------------------

#define DM 1024
#define NH 16
#define DK 64
#define LL 2048

typedef float  f32x4  __attribute__((ext_vector_type(4)));
typedef __bf16 bf16x8 __attribute__((ext_vector_type(8)));
typedef short  s16x8  __attribute__((ext_vector_type(8)));

__device__ __forceinline__ unsigned short f2bf(float f) {
    union { float f; unsigned int u; } v; v.f = f;
    return (unsigned short)((v.u + 0x7fffu + ((v.u >> 16) & 1u)) >> 16);
}
__device__ __forceinline__ unsigned int pack2(float a, float b) {
    return (unsigned int)f2bf(a) | ((unsigned int)f2bf(b) << 16);
}
__device__ __forceinline__ bf16x8 ld8(const unsigned short* p) {
    s16x8 s = *(const s16x8*)p;
    return __builtin_bit_cast(bf16x8, s);
}
__device__ __forceinline__ void gl16(const void* g, void* l) {
    __builtin_amdgcn_global_load_lds((__attribute__((address_space(1))) void*)(g),
                                     (__attribute__((address_space(3))) void*)(l),
                                     16, 0, 0);
}

// ---------------------------------------------------------------------------
// prep: 5 weight transposes (fp32 [K][N] -> bf16 [N][K]) + queries/keys
// fp32 -> bf16. Grid = 4864.
// ---------------------------------------------------------------------------
__global__ __launch_bounds__(256)
void prep_k(const float* __restrict__ Wq, const float* __restrict__ Wd,
            const float* __restrict__ Wk, const float* __restrict__ Wv,
            const float* __restrict__ Wo, const float* __restrict__ queries,
            const float* __restrict__ keys,
            unsigned short* __restrict__ WqT, unsigned short* __restrict__ WdT,
            unsigned short* __restrict__ WkvT, unsigned short* __restrict__ WoT,
            unsigned short* __restrict__ Qb, unsigned short* __restrict__ Kb) {
    int bid = blockIdx.x;
    const int t = threadIdx.x;

    const float* W; unsigned short* WT; int TK, TN;
    if (bid < 1024)      { W = Wq; WT = WqT;  TK = 1024; TN = 1024; }
    else if (bid < 1280) { bid -= 1024; W = Wd; WT = WdT; TK = 1024; TN = 256; }
    else if (bid < 1536) { bid -= 1280; W = Wk; WT = WkvT; TK = 256; TN = 1024; }
    else if (bid < 1792) { bid -= 1536; W = Wv; WT = WkvT + (size_t)1024 * 256; TK = 256; TN = 1024; }
    else if (bid < 2816) { bid -= 1792; W = Wo; WT = WoT;  TK = 1024; TN = 1024; }
    else {
        bid -= 2816;
        const float* src; unsigned short* dst;
        if (bid < 1024) { src = queries; dst = Qb; }
        else            { bid -= 1024; src = keys; dst = Kb; }
        const size_t base = (size_t)bid * 4096;
#pragma unroll
        for (int i = 0; i < 4; ++i) {
            float4 f = *(const float4*)(src + base + (size_t)(i * 256 + t) * 4);
            uint2 u = { pack2(f.x, f.y), pack2(f.z, f.w) };
            *(uint2*)(dst + base + (size_t)(i * 256 + t) * 4) = u;
        }
        return;
    }
    __shared__ float tile[32][33];
    const int tx = t & 31, ty = t >> 5;
    const int bx = bid % (TK / 32), by = bid / (TK / 32);
    const int k0 = bx * 32, n0 = by * 32;
#pragma unroll
    for (int i = 0; i < 4; ++i)
        tile[ty + 8 * i][tx] = W[(size_t)(k0 + ty + 8 * i) * TN + n0 + tx];
    __syncthreads();
#pragma unroll
    for (int i = 0; i < 4; ++i)
        WT[(size_t)(n0 + ty + 8 * i) * TK + k0 + tx] = f2bf(tile[tx][ty + 8 * i]);
}

// ---------------------------------------------------------------------------
// GEMM staging + compute helpers (128x64 tile, BK=64).
// ---------------------------------------------------------------------------
__device__ __forceinline__ void stage6(const unsigned short* gA, const unsigned short* gB,
                                       int kk, int K,
                                       unsigned short* lA, unsigned short* lB) {
#pragma unroll
    for (int s = 0; s < 4; ++s) gl16(gA + kk + (size_t)s * 8 * K, lA + s * 512);
#pragma unroll
    for (int s = 0; s < 2; ++s) gl16(gB + kk + (size_t)s * 8 * K, lB + s * 512);
}

__device__ __forceinline__ void mfma16(const unsigned short* As, const unsigned short* Bs,
                                       const int aoff[4][2], const int boff[2][2],
                                       f32x4 acc[4][2]) {
#pragma unroll
    for (int ks = 0; ks < 2; ++ks) {
        bf16x8 a[4], b[2];
#pragma unroll
        for (int i = 0; i < 4; ++i) a[i] = ld8(As + aoff[i][ks]);
#pragma unroll
        for (int j = 0; j < 2; ++j) b[j] = ld8(Bs + boff[j][ks]);
#pragma unroll
        for (int i = 0; i < 4; ++i)
#pragma unroll
            for (int j = 0; j < 2; ++j)
                acc[i][j] = __builtin_amdgcn_mfma_f32_16x16x32_bf16(a[i], b[j], acc[i][j], 0, 0, 0);
    }
}

// ---------------------------------------------------------------------------
// GEMM 128(M) x 64(N) tile, BK=64, 4 waves 2x2 (wave = 64m x 32n, 4x2 accs).
// LDS double-buffer (Sh0/Sh1, compile-time selection), one barrier per iter.
// XCD-clustered: xcd = bid&7 sweeps all n over a small m-window.
// MODE 0: fused Q+Lat (K=1024). bid<512: Qb@WqT+bq -> Qp bf16 [row*1024].
//         bid>=512 (128 blocks): Kb@WdT+bd -> Lat bf16 [row*256].
// MODE 1: Attn@WoT+bo -> f32 [row*1024]. grid 512, K=1024.
// MODE 2: fused K|V (K=256, N=2048): col<1024 -> Kp bf16 [row*1024];
//         col>=1024 -> VpT [b][col-1024][l] via LDS-transposed epilogue.
// ---------------------------------------------------------------------------
template<int MODE>
__global__ __launch_bounds__(256)
void gemm_k(const unsigned short* __restrict__ Ap, const unsigned short* __restrict__ Bt,
            const float* __restrict__ bias, void* __restrict__ Cp,
            const unsigned short* __restrict__ Ap2, const unsigned short* __restrict__ Bt2,
            const float* __restrict__ bias2, void* __restrict__ Cp2,
            int K) {
    __shared__ unsigned short Sh0[12288];     // As0 8192 + Bs0 4096 shorts (24 KB)
    __shared__ unsigned short Sh1[12288];     // As1 + Bs1 (24 KB)

    int bid = blockIdx.x;
    const unsigned short* A;
    const unsigned short* B;
    const float* bs;
    bool second = false;
    int m0, n0;
    if (MODE == 0 && bid >= 512) {            // Lat part: 128 blocks, N=256
        bid -= 512; A = Ap2; B = Bt2; bs = bias2; second = true;
        const int xcd = bid & 7, s = bid >> 3;            // s in [0,16)
        n0 = (s & 3) * 64; m0 = (xcd * 4 + (s >> 2)) * 128;
    } else {
        A = Ap; B = Bt; bs = bias;
        const int xcd = bid & 7, s = bid >> 3;
        if (MODE == 2) { n0 = (s & 31) * 64; m0 = (xcd * 4 + (s >> 5)) * 128; }
        else           { n0 = (s & 15) * 64; m0 = (xcd * 4 + (s >> 4)) * 128; }
    }

    const int t = threadIdx.x, lane = t & 63, wv = t >> 6;
    const int quad = lane >> 4, l15 = lane & 15;

    const int lr8 = lane >> 3;                 // 0..7
    const int g8 = (lane & 7) ^ (lr8 & 7);     // swizzled k-chunk
    const unsigned short* gA = A + (size_t)(m0 + wv * 32 + lr8) * K + g8 * 8;
    const unsigned short* gB = B + (size_t)(n0 + wv * 16 + lr8) * K + g8 * 8;
    unsigned short* lA0 = Sh0 + wv * 2048;
    unsigned short* lB0 = Sh0 + 8192 + wv * 1024;
    unsigned short* lA1 = Sh1 + wv * 2048;
    unsigned short* lB1 = Sh1 + 8192 + wv * 1024;

    int aoff[4][2], boff[2][2];
#pragma unroll
    for (int i = 0; i < 4; ++i) {
        const int ra = (wv >> 1) * 64 + i * 16 + l15;
#pragma unroll
        for (int ks = 0; ks < 2; ++ks)
            aoff[i][ks] = ra * 64 + (((ks * 4 + quad) ^ (ra & 7)) << 3);
    }
#pragma unroll
    for (int j = 0; j < 2; ++j) {
        const int rb = (wv & 1) * 32 + j * 16 + l15;
#pragma unroll
        for (int ks = 0; ks < 2; ++ks)
            boff[j][ks] = rb * 64 + (((ks * 4 + quad) ^ (rb & 7)) << 3);
    }

    f32x4 acc[4][2] = {};
    const int niter = K >> 6;                  // 16 or 4 (always even)

    stage6(gA, gB, 0, K, lA0, lB0);
    __syncthreads();                           // tile 0 resident in Sh0
    for (int it = 0; it < niter; it += 2) {
        const int kk = it << 6;
        // even iter: prefetch -> Sh1, compute Sh0
        if (it + 1 < niter) stage6(gA, gB, kk + 64, K, lA1, lB1);
        mfma16(Sh0, Sh0 + 8192, aoff, boff, acc);
        __syncthreads();                       // drains Sh1 gl16s (overlapped)
        if (it + 1 < niter) {
            // odd iter: prefetch -> Sh0, compute Sh1
            if (it + 2 < niter) stage6(gA, gB, kk + 128, K, lA0, lB0);
            mfma16(Sh1, Sh1 + 8192, aoff, boff, acc);
            __syncthreads();
        }
    }

    const bool isV = (MODE == 2) && (n0 >= 1024);
    if (!isV) {
#pragma unroll
        for (int j = 0; j < 2; ++j) {
            const int col = n0 + (wv & 1) * 32 + j * 16 + l15;
            const float bvv = bs[col];
#pragma unroll
            for (int i = 0; i < 4; ++i) {
                const int rowb = m0 + (wv >> 1) * 64 + i * 16 + quad * 4;
#pragma unroll
                for (int r = 0; r < 4; ++r) {
                    const float v = acc[i][j][r] + bvv;
                    const int row = rowb + r;
                    if (MODE == 1)
                        ((float*)Cp)[(size_t)row * 1024 + col] = v;
                    else if (second)
                        ((unsigned short*)Cp2)[(size_t)row * 256 + col] = f2bf(v);
                    else
                        ((unsigned short*)Cp)[(size_t)row * 1024 + col] = f2bf(v);
                }
            }
        }
    } else {
        // V part: transpose 128tok x 64d tile through LDS, store coalesced
        // to VpT[(b*1024 + d)*2048 + l].  Ld layout: [d][tok], stride 136.
        unsigned short* Ld = Sh0;               // 64*136 shorts = 17408 B
#pragma unroll
        for (int j = 0; j < 2; ++j) {
            const int dloc = (wv & 1) * 32 + j * 16 + l15;
            const float bvv = bias2[(n0 - 1024) + dloc];
#pragma unroll
            for (int i = 0; i < 4; ++i) {
                const int tokb = (wv >> 1) * 64 + i * 16 + quad * 4;
#pragma unroll
                for (int r = 0; r < 4; ++r)
                    Ld[dloc * 136 + tokb + r] = f2bf(acc[i][j][r] + bvv);
            }
        }
        __syncthreads();
        const int dloc = t >> 2;                // 0..63
        const int tk0 = (t & 3) * 32;           // 0,32,64,96
        const int bb = m0 >> 11;
        unsigned short* dst = (unsigned short*)Cp2 +
            ((size_t)bb * 1024 + (n0 - 1024) + dloc) * LL + (m0 & (LL - 1)) + tk0;
        const unsigned short* srcp = Ld + dloc * 136 + tk0;
#pragma unroll
        for (int c = 0; c < 4; ++c)
            *(uint4*)(dst + c * 8) = *(const uint4*)(srcp + c * 8);
    }
}

// ---------------------------------------------------------------------------
// Causal attention: 512 thr (2 groups of 4 waves), paired q-tiles (j, 31-j),
// even/odd 64-key chunk split, fixed-shift softmax, diag-hoisted masking.
// Grid 512, XCD-clustered (each XCD owns 4 (h,b) combos).
// ---------------------------------------------------------------------------
__global__ __launch_bounds__(512)
void attn6_k(const unsigned short* __restrict__ Qp,
             const unsigned short* __restrict__ Kp,
             const unsigned short* __restrict__ VpT,
             unsigned short* __restrict__ Op) {
    __shared__ unsigned short Ks[2][4096];
    __shared__ unsigned short Vs[2][4096];
    __shared__ unsigned short Ps[8][16][72];

    const int t = threadIdx.x, lane = t & 63, wv = t >> 6;
    const int grp = wv >> 2, w4 = wv & 3;
    const int quad = lane >> 4, l15 = lane & 15;

    const int bid = blockIdx.x;
    const int xcd = bid & 7, s = bid >> 3;
    const int pair = s & 15;
    const int combo = xcd * 4 + (s >> 4);
    const int h = combo & 15, b = combo >> 4;

    const int srow = w4 * 16 + (lane >> 3);
    const int g8 = (lane & 7) ^ ((lane >> 3) & 7);
    unsigned short* lK = &Ks[grp][w4 * 1024];
    unsigned short* lV = &Vs[grp][w4 * 1024];
    const int sw = l15 & 7;
    float* cb = (float*)&Ks[0][0];

    for (int tsel = 0; tsel < 2; ++tsel) {
        const int tile = tsel ? (31 - pair) : pair;
        const int q0 = tile * 64;

        const unsigned short* qp = Qp + (size_t)(b * LL + q0 + w4 * 16 + l15) * DM + h * DK;
        const bf16x8 aq0 = ld8(qp + quad * 8);
        const bf16x8 aq1 = ld8(qp + 32 + quad * 8);

        f32x4 acc[4] = {};
        float lrow[4] = {0.f, 0.f, 0.f, 0.f};
        const int rowq = q0 + w4 * 16 + quad * 4;

        const int nit = tile / 2 + 1;
        for (int it = 0; it < nit; ++it) {
            const int c = 2 * it + grp;
            const bool active = (c <= tile);
            const int kt = c * 64;
            __syncthreads();
            if (active) {
                const unsigned short* kg = Kp + (size_t)(b * LL + kt + srow) * DM + h * DK + g8 * 8;
                const unsigned short* vg = VpT + ((size_t)(b * NH + h) * DK + srow) * LL + kt + g8 * 8;
                gl16(kg, lK);             gl16(kg + (size_t)8 * DM, lK + 512);
                gl16(vg, lV);             gl16(vg + (size_t)8 * LL, lV + 512);
            }
            __syncthreads();
            if (!active) continue;

            f32x4 s4[4];
#pragma unroll
            for (int sub = 0; sub < 4; ++sub) {
                const int base = (sub * 16 + l15) * 64;
                f32x4 ss = {};
                bf16x8 b0 = ld8(&Ks[grp][base + ((quad ^ sw) << 3)]);
                ss = __builtin_amdgcn_mfma_f32_16x16x32_bf16(aq0, b0, ss, 0, 0, 0);
                bf16x8 b1 = ld8(&Ks[grp][base + (((4 + quad) ^ sw) << 3)]);
                ss = __builtin_amdgcn_mfma_f32_16x16x32_bf16(aq1, b1, ss, 0, 0, 0);
                s4[sub] = ss;
            }

            if (c == tile) {                   // diagonal chunk: mask
#pragma unroll
                for (int sub = 0; sub < 4; ++sub) {
                    const int col = kt + sub * 16 + l15;
#pragma unroll
                    for (int r = 0; r < 4; ++r) {
                        float e = exp2f(fmaf(s4[sub][r], 0.18033688011112042f, -16.0f));
                        if (col > rowq + r) e = 0.f;
                        lrow[r] += e;
                        Ps[wv][quad * 4 + r][sub * 16 + l15] =
                            (unsigned short)(__builtin_bit_cast(unsigned int, e) >> 16);
                    }
                }
            } else {                           // interior: no mask
#pragma unroll
                for (int sub = 0; sub < 4; ++sub) {
#pragma unroll
                    for (int r = 0; r < 4; ++r) {
                        float e = exp2f(fmaf(s4[sub][r], 0.18033688011112042f, -16.0f));
                        lrow[r] += e;
                        Ps[wv][quad * 4 + r][sub * 16 + l15] =
                            (unsigned short)(__builtin_bit_cast(unsigned int, e) >> 16);
                    }
                }
            }

#pragma unroll
            for (int ks = 0; ks < 2; ++ks) {
                bf16x8 ap = ld8(&Ps[wv][l15][ks * 32 + quad * 8]);
#pragma unroll
                for (int sub = 0; sub < 4; ++sub) {
                    bf16x8 bv = ld8(&Vs[grp][(sub * 16 + l15) * 64 + (((ks * 4 + quad) ^ sw) << 3)]);
                    acc[sub] = __builtin_amdgcn_mfma_f32_16x16x32_bf16(ap, bv, acc[sub], 0, 0, 0);
                }
            }
        }

        __syncthreads();
        const int base = (w4 * 64 + lane) * 20;
        if (grp == 1) {
#pragma unroll
            for (int sub = 0; sub < 4; ++sub)
#pragma unroll
                for (int r = 0; r < 4; ++r) cb[base + sub * 4 + r] = acc[sub][r];
#pragma unroll
            for (int r = 0; r < 4; ++r) cb[base + 16 + r] = lrow[r];
        }
        __syncthreads();
        if (grp == 0) {
#pragma unroll
            for (int sub = 0; sub < 4; ++sub)
#pragma unroll
                for (int r = 0; r < 4; ++r) acc[sub][r] += cb[base + sub * 4 + r];
#pragma unroll
            for (int r = 0; r < 4; ++r) {
                lrow[r] += cb[base + 16 + r];
#pragma unroll
                for (int off = 1; off < 16; off <<= 1)
                    lrow[r] += __shfl_xor(lrow[r], off, 64);
                lrow[r] = __builtin_amdgcn_rcpf(lrow[r]);
            }
#pragma unroll
            for (int sub = 0; sub < 4; ++sub)
#pragma unroll
                for (int r = 0; r < 4; ++r)
                    Op[(size_t)(b * LL + rowq + r) * DM + h * DK + sub * 16 + l15] =
                        f2bf(acc[sub][r] * lrow[r]);
        }
    }
}

// ---------------------------------------------------------------------------
extern "C" void kernel_launch(void* const* d_in, const int* in_sizes, int n_in,
                              void* d_out, int out_size, void* d_ws, size_t ws_size,
                              hipStream_t stream) {
    const float* queries = (const float*)d_in[0];
    const float* keys    = (const float*)d_in[1];
    const float* Wq = (const float*)d_in[3];  const float* bq = (const float*)d_in[4];
    const float* Wd = (const float*)d_in[5];  const float* bd = (const float*)d_in[6];
    const float* Wk = (const float*)d_in[7];  const float* bk = (const float*)d_in[8];
    const float* Wv = (const float*)d_in[9];  const float* bv = (const float*)d_in[10];
    const float* Wo = (const float*)d_in[11]; const float* bo = (const float*)d_in[12];

    char* ws = (char*)d_ws;
    const size_t MB = 1048576;
    unsigned short* Qp   = (unsigned short*)(ws);
    unsigned short* Kb   = (unsigned short*)(ws + 8 * MB);
    unsigned short* Kp   = (unsigned short*)(ws + 8 * MB);
    unsigned short* Qb   = (unsigned short*)(ws + 16 * MB);
    unsigned short* VpT  = (unsigned short*)(ws + 16 * MB);
    unsigned short* WqT  = (unsigned short*)(ws + 24 * MB);
    unsigned short* Lat  = (unsigned short*)(ws + 26 * MB);
    unsigned short* WdT  = (unsigned short*)(ws + 28 * MB);
    unsigned short* WkvT = (unsigned short*)(ws + 28 * MB + 524288);
    unsigned short* Attn = (unsigned short*)(ws + 24 * MB);
    unsigned short* WoT  = (unsigned short*)(ws + 32 * MB);

    prep_k<<<4864, 256, 0, stream>>>(Wq, Wd, Wk, Wv, Wo, queries, keys,
                                     WqT, WdT, WkvT, WoT, Qb, Kb);
    gemm_k<0><<<640, 256, 0, stream>>>(Qb, WqT, bq, Qp, Kb, WdT, bd, Lat, 1024);
    gemm_k<2><<<1024, 256, 0, stream>>>(Lat, WkvT, bk, Kp, nullptr, nullptr, bv, VpT, 256);
    attn6_k<<<512, 512, 0, stream>>>(Qp, Kp, VpT, Attn);
    gemm_k<1><<<512, 256, 0, stream>>>(Attn, WoT, bo, d_out, nullptr, nullptr, nullptr, nullptr, 1024);
}